// Round 6
// baseline (3348.304 us; speedup 1.0000x reference)
//
#include <hip/hip_runtime.h>
#include <hip/hip_bf16.h>
#include <stdint.h>

#define H 2048
#define FOURH 8192
#define NT 768
#define NS 256

typedef __attribute__((ext_vector_type(8))) short bf16x8;
typedef __attribute__((ext_vector_type(4))) float f32x4;
typedef __attribute__((ext_vector_type(4))) unsigned uint4v;
typedef unsigned long long u64;

static __device__ __forceinline__ unsigned short f2bf(float x) {
  unsigned u = __float_as_uint(x);
  return (unsigned short)((u + 0x7fffu + ((u >> 16) & 1u)) >> 16);
}
static __device__ __forceinline__ unsigned pk2(float lo, float hi) {
  return ((unsigned)f2bf(hi) << 16) | (unsigned)f2bf(lo);
}
static __device__ __forceinline__ float bflo(unsigned u) { return __uint_as_float(u << 16); }
static __device__ __forceinline__ float bfhi(unsigned u) { return __uint_as_float(u & 0xffff0000u); }
static __device__ __forceinline__ float sigm(float x) { return 1.f / (1.f + __expf(-x)); }
static __device__ __forceinline__ float tanh_fast(float x) {
  float xc = fminf(fmaxf(x, -15.f), 15.f);
  float e = __expf(2.f * xc);
  return (e - 1.f) / (e + 1.f);
}

// ---------------- gather: build X_bf16[768][2048] ----------------
__global__ void gather_x(const int* __restrict__ ctx, const int* __restrict__ f1,
                         const int* __restrict__ f2, const float* __restrict__ ctx_table,
                         const float* __restrict__ face_table, unsigned short* __restrict__ X) {
  int t = blockIdx.x;            // 0..767
  int s = t / 3, k = t - 3 * s;  // sample, sub-step
  const float* src;
  if (k == 0)      src = ctx_table  + (size_t)ctx[s] * H;
  else if (k == 1) src = face_table + (size_t)f1[s] * H;
  else             src = face_table + (size_t)f2[s] * H;
  int c = threadIdx.x * 8;
  float4 v0 = *(const float4*)(src + c);
  float4 v1 = *(const float4*)(src + c + 4);
  uint4 o;
  o.x = pk2(v0.x, v0.y); o.y = pk2(v0.z, v0.w);
  o.z = pk2(v1.x, v1.y); o.w = pk2(v1.z, v1.w);
  *(uint4*)(X + (size_t)t * H + c) = o;
}

// ---------------- GEMM: P[768][8192] = X @ W_ih^T + (b_ih + b_hh) ----------------
__launch_bounds__(256)
__global__ void gemm_p(const unsigned short* __restrict__ X, const float* __restrict__ Wih,
                       const float* __restrict__ bih, const float* __restrict__ bhh,
                       float* __restrict__ P) {
  __shared__ unsigned short Alds[128 * 32];
  __shared__ unsigned short Blds[128 * 32];
  int tid = threadIdx.x;
  int bm = (blockIdx.x >> 6) * 128;   // 6 M-tiles
  int bn = (blockIdx.x & 63) * 128;   // 64 N-tiles
  int w = tid >> 6, l = tid & 63;
  int wm = (w >> 1) * 64, wn = (w & 1) * 64;
  int sr = tid >> 1;             // staging row 0..127
  int sc = (tid & 1) * 16;       // staging col 0 / 16
  int cl = l & 15, kg = (l >> 4) * 8;

  f32x4 acc[4][4];
#pragma unroll
  for (int i = 0; i < 4; ++i)
#pragma unroll
    for (int j = 0; j < 4; ++j) acc[i][j] = (f32x4){0.f, 0.f, 0.f, 0.f};

  for (int kt = 0; kt < H; kt += 32) {
    __syncthreads();
    const unsigned short* ap = X + (size_t)(bm + sr) * H + kt + sc;
    uint4 a0 = *(const uint4*)ap;
    uint4 a1 = *(const uint4*)(ap + 8);
    const float* bp = Wih + (size_t)(bn + sr) * H + kt + sc;
    float4 f0 = *(const float4*)bp;
    float4 f1v = *(const float4*)(bp + 4);
    float4 f2v = *(const float4*)(bp + 8);
    float4 f3v = *(const float4*)(bp + 12);
    *(uint4*)(Alds + sr * 32 + sc) = a0;
    *(uint4*)(Alds + sr * 32 + sc + 8) = a1;
    uint4 b0, b1;
    b0.x = pk2(f0.x, f0.y);  b0.y = pk2(f0.z, f0.w);
    b0.z = pk2(f1v.x, f1v.y); b0.w = pk2(f1v.z, f1v.w);
    b1.x = pk2(f2v.x, f2v.y); b1.y = pk2(f2v.z, f2v.w);
    b1.z = pk2(f3v.x, f3v.y); b1.w = pk2(f3v.z, f3v.w);
    *(uint4*)(Blds + sr * 32 + sc) = b0;
    *(uint4*)(Blds + sr * 32 + sc + 8) = b1;
    __syncthreads();

    bf16x8 af[4], bb[4];
#pragma unroll
    for (int i = 0; i < 4; ++i) {
      af[i] = *(bf16x8*)(Alds + (wm + i * 16 + cl) * 32 + kg);
      bb[i] = *(bf16x8*)(Blds + (wn + i * 16 + cl) * 32 + kg);
    }
#pragma unroll
    for (int i = 0; i < 4; ++i)
#pragma unroll
      for (int j = 0; j < 4; ++j)
        acc[i][j] = __builtin_amdgcn_mfma_f32_16x16x32_bf16(af[i], bb[j], acc[i][j], 0, 0, 0);
  }

  int rg = (l >> 4) * 4;
#pragma unroll
  for (int j = 0; j < 4; ++j) {
    int n = bn + wn + j * 16 + cl;
    float bias = bih[n] + bhh[n];
#pragma unroll
    for (int i = 0; i < 4; ++i) {
      int m = bm + wm + i * 16 + rg;
#pragma unroll
      for (int r = 0; r < 4; ++r)
        P[(size_t)(m + r) * FOURH + n] = acc[i][j][r] + bias;
    }
  }
}

// ---------------- persistent sequential LSTM ----------------
// 256 WGs x 256 threads, 1 WG/CU. WG g owns h elements [g*8, g*8+8).
// Wave G owns gate G's 8 rows; lane l owns cols {j*256 + l*4 + 0..3}.
// Weights in VGPRs (128 packed-bf16-pair regs/thread).
// Broadcast: hbuf[2][2048] u32 = (tag16<<16 | bf16(h)). All global-tier
// traffic is COALESCED VECTOR ops with device-scope (sc0 sc1) semantics:
//  - producers: lane 0 packs the WG's 8 contiguous tagged words (shfl) and
//    issues 2x global_store_dwordx4 sc0 sc1 (512 store txns/step vs 2048).
//  - importers (WGs 0..7, round-robin -> XCDs 0..7): poll hbuf with 2x
//    global_load_dwordx4 sc0 sc1 per thread (~8 reqs/line/round at LLC vs
//    ~512 with atomic dwords), then re-publish into hloc[g] (own-XCD L2)
//    with plain write-back stores.
//  - consumers: poll hloc[g&7] with sc0-only dwordx4 (L2-served); tag check
//    retries stale/torn reads; fallback to global poll if mapping is wrong.
__launch_bounds__(256, 1)
__global__ void lstm_seq(const float* __restrict__ Whh, const float* __restrict__ P,
                         unsigned* __restrict__ hbuf, unsigned* __restrict__ hloc,
                         float* __restrict__ hs, float* __restrict__ out) {
  __shared__ float h_lds[H];
  __shared__ float gates_lds[2][32];
  int g = blockIdx.x;
  int tid = threadIdx.x;
  int G = tid >> 6, l = tid & 63;

  // one-time weight load: rows G*2048 + g*8 + q, cols j*256 + l*4 + 0..3
  unsigned wpk[8][8][2];
#pragma unroll
  for (int q = 0; q < 8; ++q) {
    const float* wrow = Whh + (size_t)(G * H + g * 8 + q) * H;
#pragma unroll
    for (int j = 0; j < 8; ++j) {
      float4 wv = *(const float4*)(wrow + j * 256 + l * 4);
      wpk[q][j][0] = pk2(wv.x, wv.y);
      wpk[q][j][1] = pk2(wv.z, wv.w);
    }
  }

  float c_state = 0.f;  // valid for tid < 8

  for (int t = 0; t < NT; ++t) {
    // independent P-row fetch first (overlaps the poll); wave 0 only
    float p_v = 0.f;
    if (tid < 32)
      p_v = P[(size_t)t * FOURH + (size_t)(tid >> 3) * H + g * 8 + (tid & 7)];

    // ---- two-tier tagged poll for this thread's 8 h-words ----
    unsigned v[8];
    {
      unsigned want = ((unsigned)t & 0xffffu) << 16;
      const unsigned* srcg = hbuf + (size_t)(t & 1) * H + tid * 8;
      if (g < 8) {
        // importer: coalesced device-scope vector poll of global hbuf
        for (;;) {
          uint4v a, b;
          asm volatile(
              "global_load_dwordx4 %0, %2, off sc0 sc1\n\t"
              "global_load_dwordx4 %1, %3, off sc0 sc1\n\t"
              "s_waitcnt vmcnt(0)"
              : "=&v"(a), "=&v"(b)
              : "v"(srcg), "v"(srcg + 4)
              : "memory");
          unsigned m = ((a.x ^ want) | (a.y ^ want) | (a.z ^ want) | (a.w ^ want) |
                        (b.x ^ want) | (b.y ^ want) | (b.z ^ want) | (b.w ^ want)) &
                       0xffff0000u;
          if (m == 0) {
            v[0] = a.x; v[1] = a.y; v[2] = a.z; v[3] = a.w;
            v[4] = b.x; v[5] = b.y; v[6] = b.z; v[7] = b.w;
            break;
          }
          __builtin_amdgcn_s_sleep(1);
        }
        // re-publish into this XCD's replica (plain write-back -> own L2)
        unsigned* ldst = hloc + ((size_t)g * 2 + (t & 1)) * H + tid * 8;
        *(uint4*)ldst = make_uint4(v[0], v[1], v[2], v[3]);
        *(uint4*)(ldst + 4) = make_uint4(v[4], v[5], v[6], v[7]);
      } else {
        // consumer: poll local XCD replica (L2), fallback to global
        const unsigned* lsrc = hloc + ((size_t)(g & 7) * 2 + (t & 1)) * H + tid * 8;
        int rounds = 0;
        for (;;) {
          uint4v a, b;
          asm volatile(
              "global_load_dwordx4 %0, %2, off sc0\n\t"
              "global_load_dwordx4 %1, %3, off sc0\n\t"
              "s_waitcnt vmcnt(0)"
              : "=&v"(a), "=&v"(b)
              : "v"(lsrc), "v"(lsrc + 4)
              : "memory");
          unsigned m = ((a.x ^ want) | (a.y ^ want) | (a.z ^ want) | (a.w ^ want) |
                        (b.x ^ want) | (b.y ^ want) | (b.z ^ want) | (b.w ^ want)) &
                       0xffff0000u;
          if (m == 0) {
            v[0] = a.x; v[1] = a.y; v[2] = a.z; v[3] = a.w;
            v[4] = b.x; v[5] = b.y; v[6] = b.z; v[7] = b.w;
            break;
          }
          if (++rounds >= 8) {  // mapping/semantics fallback: always correct
            uint4v ga, gb;
            asm volatile(
                "global_load_dwordx4 %0, %2, off sc0 sc1\n\t"
                "global_load_dwordx4 %1, %3, off sc0 sc1\n\t"
                "s_waitcnt vmcnt(0)"
                : "=&v"(ga), "=&v"(gb)
                : "v"(srcg), "v"(srcg + 4)
                : "memory");
            unsigned gm = ((ga.x ^ want) | (ga.y ^ want) | (ga.z ^ want) | (ga.w ^ want) |
                           (gb.x ^ want) | (gb.y ^ want) | (gb.z ^ want) | (gb.w ^ want)) &
                          0xffff0000u;
            if (gm == 0) {
              v[0] = ga.x; v[1] = ga.y; v[2] = ga.z; v[3] = ga.w;
              v[4] = gb.x; v[5] = gb.y; v[6] = gb.z; v[7] = gb.w;
              break;
            }
          }
          __builtin_amdgcn_s_sleep(1);
        }
      }
      *(float4*)&h_lds[tid * 8] =
          make_float4(__uint_as_float(v[0] << 16), __uint_as_float(v[1] << 16),
                      __uint_as_float(v[2] << 16), __uint_as_float(v[3] << 16));
      *(float4*)&h_lds[tid * 8 + 4] =
          make_float4(__uint_as_float(v[4] << 16), __uint_as_float(v[5] << 16),
                      __uint_as_float(v[6] << 16), __uint_as_float(v[7] << 16));
    }
    __syncthreads();

    // matvec: 8 rows x 32 cols per thread
    float acc[8] = {0.f, 0.f, 0.f, 0.f, 0.f, 0.f, 0.f, 0.f};
#pragma unroll
    for (int j = 0; j < 8; ++j) {
      float4 hj = *(float4*)&h_lds[j * 256 + l * 4];
#pragma unroll
      for (int q = 0; q < 8; ++q) {
        unsigned u0 = wpk[q][j][0], u1 = wpk[q][j][1];
        acc[q] += bflo(u0) * hj.x + bfhi(u0) * hj.y + bflo(u1) * hj.z + bfhi(u1) * hj.w;
      }
    }
    // butterfly reduce over the wave (cols)
#pragma unroll
    for (int q = 0; q < 8; ++q) {
      float v2 = acc[q];
#pragma unroll
      for (int off = 1; off < 64; off <<= 1) v2 += __shfl_xor(v2, off, 64);
      acc[q] = v2;
    }
    if (l == 0) {
#pragma unroll
      for (int q = 0; q < 8; ++q) gates_lds[t & 1][G * 8 + q] = acc[q];
    }

    // wave 0: distribute the 4 gate biases of row (g*8 + tid&7) via shfl
    float pre_i = 0.f, pre_f = 0.f, pre_g = 0.f, pre_o = 0.f;
    if (tid < 64) {
      int q = tid & 7;
      pre_i = __shfl(p_v, q, 64);
      pre_f = __shfl(p_v, 8 + q, 64);
      pre_g = __shfl(p_v, 16 + q, 64);
      pre_o = __shfl(p_v, 24 + q, 64);
    }
    __syncthreads();

    // gate finish on wave-0 lanes 0..7; lane 0 packs + stores (2x dwordx4)
    if (tid < 64) {
      unsigned wword = 0;
      if (l < 8) {
        int q = l;
        float iv = sigm(gates_lds[t & 1][q]      + pre_i);
        float fv = sigm(gates_lds[t & 1][8 + q]  + pre_f);
        float gv = tanh_fast(gates_lds[t & 1][16 + q] + pre_g);
        float ov = sigm(gates_lds[t & 1][24 + q] + pre_o);
        c_state = fv * c_state + iv * gv;
        float hnew = ov * tanh_fast(c_state);
        wword = ((((unsigned)(t + 1)) & 0xffffu) << 16) | (unsigned)f2bf(hnew);
        int m3 = t - (t / 3) * 3;
        if (m3 == 2) hs[(size_t)(t / 3) * H + g * 8 + q] = hnew;
        if (t == NT - 1) {
          out[512 + g * 8 + q] = hnew;        // hF
          out[512 + H + g * 8 + q] = c_state; // cF
        }
      }
      unsigned w0 = __shfl(wword, 0, 64), w1 = __shfl(wword, 1, 64);
      unsigned w2 = __shfl(wword, 2, 64), w3 = __shfl(wword, 3, 64);
      unsigned w4 = __shfl(wword, 4, 64), w5 = __shfl(wword, 5, 64);
      unsigned w6 = __shfl(wword, 6, 64), w7 = __shfl(wword, 7, 64);
      if (l == 0) {
        unsigned* dst = hbuf + (size_t)((t + 1) & 1) * H + g * 8;
        uint4v a; a.x = w0; a.y = w1; a.z = w2; a.w = w3;
        uint4v b; b.x = w4; b.y = w5; b.z = w6; b.w = w7;
        asm volatile(
            "global_store_dwordx4 %0, %2, off sc0 sc1\n\t"
            "global_store_dwordx4 %1, %3, off sc0 sc1"
            :
            : "v"(dst), "v"(dst + 4), "v"(a), "v"(b)
            : "memory");
      }
    }
  }
}

// ---------------- readout: outputs[256][2] ----------------
__global__ void out_head(const float* __restrict__ hs, const float* __restrict__ Wout,
                         const float* __restrict__ bout, float* __restrict__ out) {
  int s = blockIdx.x;
  int l = threadIdx.x;  // 64
  float a0 = 0.f, a1 = 0.f;
#pragma unroll 4
  for (int j = 0; j < 32; ++j) {
    int idx = j * 64 + l;
    float h = hs[(size_t)s * H + idx];
    a0 += h * Wout[idx];
    a1 += h * Wout[H + idx];
  }
#pragma unroll
  for (int off = 1; off < 64; off <<= 1) {
    a0 += __shfl_xor(a0, off, 64);
    a1 += __shfl_xor(a1, off, 64);
  }
  if (l == 0) {
    out[s * 2]     = a0 + bout[0];
    out[s * 2 + 1] = a1 + bout[1];
  }
}

extern "C" void kernel_launch(void* const* d_in, const int* in_sizes, int n_in,
                              void* d_out, int out_size, void* d_ws, size_t ws_size,
                              hipStream_t stream) {
  const int*   ctx        = (const int*)d_in[0];
  const int*   f1         = (const int*)d_in[1];
  const int*   f2         = (const int*)d_in[2];
  const float* ctx_table  = (const float*)d_in[3];
  const float* face_table = (const float*)d_in[4];
  const float* Wih        = (const float*)d_in[5];
  const float* Whh        = (const float*)d_in[6];
  const float* bih        = (const float*)d_in[7];
  const float* bhh        = (const float*)d_in[8];
  const float* Wout       = (const float*)d_in[9];
  const float* bout       = (const float*)d_in[10];
  float* out = (float*)d_out;

  char* ws = (char*)d_ws;
  size_t off = 0;
  unsigned short* X = (unsigned short*)(ws + off); off += (size_t)NT * H * 2;  // 3,145,728
  float* P    = (float*)(ws + off); off += (size_t)NT * FOURH * 4;             // 25,165,824
  unsigned* hbuf = (unsigned*)(ws + off); off += (size_t)2 * H * 4;            // 16,384
  unsigned* hloc = (unsigned*)(ws + off); off += (size_t)8 * 2 * H * 4;        // 131,072
  float* hs   = (float*)(ws + off); off += (size_t)NS * H * 4;                 // 2,097,152

  // zero tags: parity-0 tag0/value0 is valid t=0 data; kills stale tags on replay
  hipMemsetAsync(hbuf, 0, (size_t)2 * H * 4, stream);
  hipMemsetAsync(hloc, 0, (size_t)8 * 2 * H * 4, stream);

  gather_x<<<NT, 256, 0, stream>>>(ctx, f1, f2, ctx_table, face_table, X);
  gemm_p<<<6 * 64, 256, 0, stream>>>(X, Wih, bih, bhh, P);
  lstm_seq<<<NS, 256, 0, stream>>>(Whh, P, hbuf, hloc, hs, out);
  out_head<<<NS, 64, 0, stream>>>(hs, Wout, bout, out);
}

// Round 7
// 2884.145 us; speedup vs baseline: 1.1609x; 1.1609x over previous
//
#include <hip/hip_runtime.h>
#include <hip/hip_bf16.h>
#include <stdint.h>

#define H 2048
#define FOURH 8192
#define NT 768
#define NS 256

typedef __attribute__((ext_vector_type(8))) short bf16x8;
typedef __attribute__((ext_vector_type(4))) float f32x4;
typedef __attribute__((ext_vector_type(4))) unsigned uint4v;

static __device__ __forceinline__ unsigned short f2bf(float x) {
  unsigned u = __float_as_uint(x);
  return (unsigned short)((u + 0x7fffu + ((u >> 16) & 1u)) >> 16);
}
static __device__ __forceinline__ unsigned pk2(float lo, float hi) {
  return ((unsigned)f2bf(hi) << 16) | (unsigned)f2bf(lo);
}
static __device__ __forceinline__ float bflo(unsigned u) { return __uint_as_float(u << 16); }
static __device__ __forceinline__ float bfhi(unsigned u) { return __uint_as_float(u & 0xffff0000u); }
static __device__ __forceinline__ float sigm(float x) { return 1.f / (1.f + __expf(-x)); }
static __device__ __forceinline__ float tanh_fast(float x) {
  float xc = fminf(fmaxf(x, -15.f), 15.f);
  float e = __expf(2.f * xc);
  return (e - 1.f) / (e + 1.f);
}

// ---------------- gather: build X_bf16[768][2048] ----------------
__global__ void gather_x(const int* __restrict__ ctx, const int* __restrict__ f1,
                         const int* __restrict__ f2, const float* __restrict__ ctx_table,
                         const float* __restrict__ face_table, unsigned short* __restrict__ X) {
  int t = blockIdx.x;            // 0..767
  int s = t / 3, k = t - 3 * s;  // sample, sub-step
  const float* src;
  if (k == 0)      src = ctx_table  + (size_t)ctx[s] * H;
  else if (k == 1) src = face_table + (size_t)f1[s] * H;
  else             src = face_table + (size_t)f2[s] * H;
  int c = threadIdx.x * 8;
  float4 v0 = *(const float4*)(src + c);
  float4 v1 = *(const float4*)(src + c + 4);
  uint4 o;
  o.x = pk2(v0.x, v0.y); o.y = pk2(v0.z, v0.w);
  o.z = pk2(v1.x, v1.y); o.w = pk2(v1.z, v1.w);
  *(uint4*)(X + (size_t)t * H + c) = o;
}

// ---------------- GEMM: P[768][8192] = X @ W_ih^T + (b_ih + b_hh) ----------------
__launch_bounds__(256)
__global__ void gemm_p(const unsigned short* __restrict__ X, const float* __restrict__ Wih,
                       const float* __restrict__ bih, const float* __restrict__ bhh,
                       float* __restrict__ P) {
  __shared__ unsigned short Alds[128 * 32];
  __shared__ unsigned short Blds[128 * 32];
  int tid = threadIdx.x;
  int bm = (blockIdx.x >> 6) * 128;   // 6 M-tiles
  int bn = (blockIdx.x & 63) * 128;   // 64 N-tiles
  int w = tid >> 6, l = tid & 63;
  int wm = (w >> 1) * 64, wn = (w & 1) * 64;
  int sr = tid >> 1;             // staging row 0..127
  int sc = (tid & 1) * 16;       // staging col 0 / 16
  int cl = l & 15, kg = (l >> 4) * 8;

  f32x4 acc[4][4];
#pragma unroll
  for (int i = 0; i < 4; ++i)
#pragma unroll
    for (int j = 0; j < 4; ++j) acc[i][j] = (f32x4){0.f, 0.f, 0.f, 0.f};

  for (int kt = 0; kt < H; kt += 32) {
    __syncthreads();
    const unsigned short* ap = X + (size_t)(bm + sr) * H + kt + sc;
    uint4 a0 = *(const uint4*)ap;
    uint4 a1 = *(const uint4*)(ap + 8);
    const float* bp = Wih + (size_t)(bn + sr) * H + kt + sc;
    float4 f0 = *(const float4*)bp;
    float4 f1v = *(const float4*)(bp + 4);
    float4 f2v = *(const float4*)(bp + 8);
    float4 f3v = *(const float4*)(bp + 12);
    *(uint4*)(Alds + sr * 32 + sc) = a0;
    *(uint4*)(Alds + sr * 32 + sc + 8) = a1;
    uint4 b0, b1;
    b0.x = pk2(f0.x, f0.y);  b0.y = pk2(f0.z, f0.w);
    b0.z = pk2(f1v.x, f1v.y); b0.w = pk2(f1v.z, f1v.w);
    b1.x = pk2(f2v.x, f2v.y); b1.y = pk2(f2v.z, f2v.w);
    b1.z = pk2(f3v.x, f3v.y); b1.w = pk2(f3v.z, f3v.w);
    *(uint4*)(Blds + sr * 32 + sc) = b0;
    *(uint4*)(Blds + sr * 32 + sc + 8) = b1;
    __syncthreads();

    bf16x8 af[4], bb[4];
#pragma unroll
    for (int i = 0; i < 4; ++i) {
      af[i] = *(bf16x8*)(Alds + (wm + i * 16 + cl) * 32 + kg);
      bb[i] = *(bf16x8*)(Blds + (wn + i * 16 + cl) * 32 + kg);
    }
#pragma unroll
    for (int i = 0; i < 4; ++i)
#pragma unroll
      for (int j = 0; j < 4; ++j)
        acc[i][j] = __builtin_amdgcn_mfma_f32_16x16x32_bf16(af[i], bb[j], acc[i][j], 0, 0, 0);
  }

  int rg = (l >> 4) * 4;
#pragma unroll
  for (int j = 0; j < 4; ++j) {
    int n = bn + wn + j * 16 + cl;
    float bias = bih[n] + bhh[n];
#pragma unroll
    for (int i = 0; i < 4; ++i) {
      int m = bm + wm + i * 16 + rg;
#pragma unroll
      for (int r = 0; r < 4; ++r)
        P[(size_t)(m + r) * FOURH + n] = acc[i][j][r] + bias;
    }
  }
}

// ---------------- persistent sequential LSTM ----------------
// 256 WGs x 256 threads, 1 WG/CU. WG g owns h elements [g*8, g*8+8).
// Wave G owns gate G's 8 rows; lane l owns cols {j*256 + l*4 + 0..3}.
// Weights in VGPRs (128 packed-bf16-pair regs/thread).
// PUSH-BASED REPLICATION: hrep[8][2][2048] u32 = (tag16<<16 | bf16(h)).
// Producers: after the gate math, lanes 0..7 of wave 0 each store the WG's
// 8 contiguous tagged words into replica l (2x global_store_dwordx4 sc0 sc1,
// 8 replicas in flight concurrently -- visibility paid once, no pull hop).
// Consumers: poll ONLY replica (g&7) with sc0 sc1 dwordx4 (LLC-served;
// sc0-only would deadlock on a permanently-stale own-L2 line). Per-line
// fan-out ~32 requesters, same as R5's importer tier, but one hop shorter.
// Any replica holds full data, so mapping is correctness-irrelevant.
__launch_bounds__(256, 1)
__global__ void lstm_seq(const float* __restrict__ Whh, const float* __restrict__ P,
                         unsigned* __restrict__ hrep, float* __restrict__ hs,
                         float* __restrict__ out) {
  __shared__ float h_lds[H];
  __shared__ float gates_lds[2][32];
  int g = blockIdx.x;
  int tid = threadIdx.x;
  int G = tid >> 6, l = tid & 63;

  // one-time weight load: rows G*2048 + g*8 + q, cols j*256 + l*4 + 0..3
  unsigned wpk[8][8][2];
#pragma unroll
  for (int q = 0; q < 8; ++q) {
    const float* wrow = Whh + (size_t)(G * H + g * 8 + q) * H;
#pragma unroll
    for (int j = 0; j < 8; ++j) {
      float4 wv = *(const float4*)(wrow + j * 256 + l * 4);
      wpk[q][j][0] = pk2(wv.x, wv.y);
      wpk[q][j][1] = pk2(wv.z, wv.w);
    }
  }

  float c_state = 0.f;  // valid on wave-0 lanes 0..7
  const unsigned* myrep = hrep + (size_t)(g & 7) * 2 * H;

  for (int t = 0; t < NT; ++t) {
    // independent P-row fetch first (overlaps the poll); wave 0 only
    float p_v = 0.f;
    if (tid < 32)
      p_v = P[(size_t)t * FOURH + (size_t)(tid >> 3) * H + g * 8 + (tid & 7)];

    // poll own 32B slice of replica (g&7), parity t&1
    {
      const unsigned* src = myrep + (size_t)(t & 1) * H + tid * 8;
      unsigned want = ((unsigned)t & 0xffffu) << 16;
      uint4v a, b;
      for (;;) {
        asm volatile(
            "global_load_dwordx4 %0, %2, off sc0 sc1\n\t"
            "global_load_dwordx4 %1, %3, off sc0 sc1\n\t"
            "s_waitcnt vmcnt(0)"
            : "=&v"(a), "=&v"(b)
            : "v"(src), "v"(src + 4)
            : "memory");
        unsigned m = ((a.x ^ want) | (a.y ^ want) | (a.z ^ want) | (a.w ^ want) |
                      (b.x ^ want) | (b.y ^ want) | (b.z ^ want) | (b.w ^ want)) &
                     0xffff0000u;
        if (m == 0) break;
        __builtin_amdgcn_s_sleep(1);
      }
      *(float4*)&h_lds[tid * 8] =
          make_float4(__uint_as_float(a.x << 16), __uint_as_float(a.y << 16),
                      __uint_as_float(a.z << 16), __uint_as_float(a.w << 16));
      *(float4*)&h_lds[tid * 8 + 4] =
          make_float4(__uint_as_float(b.x << 16), __uint_as_float(b.y << 16),
                      __uint_as_float(b.z << 16), __uint_as_float(b.w << 16));
    }
    __syncthreads();

    // matvec: 8 rows x 32 cols per thread
    float acc[8] = {0.f, 0.f, 0.f, 0.f, 0.f, 0.f, 0.f, 0.f};
#pragma unroll
    for (int j = 0; j < 8; ++j) {
      float4 hj = *(float4*)&h_lds[j * 256 + l * 4];
#pragma unroll
      for (int q = 0; q < 8; ++q) {
        unsigned u0 = wpk[q][j][0], u1 = wpk[q][j][1];
        acc[q] += bflo(u0) * hj.x + bfhi(u0) * hj.y + bflo(u1) * hj.z + bfhi(u1) * hj.w;
      }
    }
    // butterfly reduce over the wave (cols)
#pragma unroll
    for (int q = 0; q < 8; ++q) {
      float v2 = acc[q];
#pragma unroll
      for (int off = 1; off < 64; off <<= 1) v2 += __shfl_xor(v2, off, 64);
      acc[q] = v2;
    }
    if (l == 0) {
#pragma unroll
      for (int q = 0; q < 8; ++q) gates_lds[t & 1][G * 8 + q] = acc[q];
    }

    // wave 0: distribute the 4 gate biases of row (g*8 + tid&7) via shfl
    float pre_i = 0.f, pre_f = 0.f, pre_g = 0.f, pre_o = 0.f;
    if (tid < 64) {
      int q = tid & 7;
      pre_i = __shfl(p_v, q, 64);
      pre_f = __shfl(p_v, 8 + q, 64);
      pre_g = __shfl(p_v, 16 + q, 64);
      pre_o = __shfl(p_v, 24 + q, 64);
    }
    __syncthreads();

    // wave 0: gate finish on lanes 0..7, then PUSH to all 8 replicas
    if (tid < 64) {
      unsigned wword = 0;
      if (l < 8) {
        int q = l;
        float iv = sigm(gates_lds[t & 1][q]      + pre_i);
        float fv = sigm(gates_lds[t & 1][8 + q]  + pre_f);
        float gv = tanh_fast(gates_lds[t & 1][16 + q] + pre_g);
        float ov = sigm(gates_lds[t & 1][24 + q] + pre_o);
        c_state = fv * c_state + iv * gv;
        float hnew = ov * tanh_fast(c_state);
        wword = ((((unsigned)(t + 1)) & 0xffffu) << 16) | (unsigned)f2bf(hnew);
        int m3 = t - (t / 3) * 3;
        if (m3 == 2) hs[(size_t)(t / 3) * H + g * 8 + q] = hnew;
        if (t == NT - 1) {
          out[512 + g * 8 + q] = hnew;        // hF
          out[512 + H + g * 8 + q] = c_state; // cF
        }
      }
      unsigned w0 = __shfl(wword, 0, 64), w1 = __shfl(wword, 1, 64);
      unsigned w2 = __shfl(wword, 2, 64), w3 = __shfl(wword, 3, 64);
      unsigned w4 = __shfl(wword, 4, 64), w5 = __shfl(wword, 5, 64);
      unsigned w6 = __shfl(wword, 6, 64), w7 = __shfl(wword, 7, 64);
      if (l < 8) {
        // lane r pushes the WG's full 8-word slot into replica r
        unsigned* dst = hrep + ((size_t)l * 2 + ((t + 1) & 1)) * H + g * 8;
        uint4v A, B;
        A.x = w0; A.y = w1; A.z = w2; A.w = w3;
        B.x = w4; B.y = w5; B.z = w6; B.w = w7;
        asm volatile(
            "global_store_dwordx4 %0, %2, off sc0 sc1\n\t"
            "global_store_dwordx4 %1, %3, off sc0 sc1"
            :
            : "v"(dst), "v"(dst + 4), "v"(A), "v"(B)
            : "memory");
      }
    }
  }
}

// ---------------- readout: outputs[256][2] ----------------
__global__ void out_head(const float* __restrict__ hs, const float* __restrict__ Wout,
                         const float* __restrict__ bout, float* __restrict__ out) {
  int s = blockIdx.x;
  int l = threadIdx.x;  // 64
  float a0 = 0.f, a1 = 0.f;
#pragma unroll 4
  for (int j = 0; j < 32; ++j) {
    int idx = j * 64 + l;
    float h = hs[(size_t)s * H + idx];
    a0 += h * Wout[idx];
    a1 += h * Wout[H + idx];
  }
#pragma unroll
  for (int off = 1; off < 64; off <<= 1) {
    a0 += __shfl_xor(a0, off, 64);
    a1 += __shfl_xor(a1, off, 64);
  }
  if (l == 0) {
    out[s * 2]     = a0 + bout[0];
    out[s * 2 + 1] = a1 + bout[1];
  }
}

extern "C" void kernel_launch(void* const* d_in, const int* in_sizes, int n_in,
                              void* d_out, int out_size, void* d_ws, size_t ws_size,
                              hipStream_t stream) {
  const int*   ctx        = (const int*)d_in[0];
  const int*   f1         = (const int*)d_in[1];
  const int*   f2         = (const int*)d_in[2];
  const float* ctx_table  = (const float*)d_in[3];
  const float* face_table = (const float*)d_in[4];
  const float* Wih        = (const float*)d_in[5];
  const float* Whh        = (const float*)d_in[6];
  const float* bih        = (const float*)d_in[7];
  const float* bhh        = (const float*)d_in[8];
  const float* Wout       = (const float*)d_in[9];
  const float* bout       = (const float*)d_in[10];
  float* out = (float*)d_out;

  char* ws = (char*)d_ws;
  size_t off = 0;
  unsigned short* X = (unsigned short*)(ws + off); off += (size_t)NT * H * 2;  // 3,145,728
  float* P    = (float*)(ws + off); off += (size_t)NT * FOURH * 4;             // 25,165,824
  unsigned* hrep = (unsigned*)(ws + off); off += (size_t)8 * 2 * H * 4;        // 131,072
  float* hs   = (float*)(ws + off); off += (size_t)NS * H * 4;                 // 2,097,152

  // zero tags in all replicas: parity-0 tag0/value0 is valid t=0 data (h=0);
  // kills stale tags on graph replay
  hipMemsetAsync(hrep, 0, (size_t)8 * 2 * H * 4, stream);

  gather_x<<<NT, 256, 0, stream>>>(ctx, f1, f2, ctx_table, face_table, X);
  gemm_p<<<6 * 64, 256, 0, stream>>>(X, Wih, bih, bhh, P);
  lstm_seq<<<NS, 256, 0, stream>>>(Whh, P, hrep, hs, out);
  out_head<<<NS, 64, 0, stream>>>(hs, Wout, bout, out);
}